// Round 13
// baseline (197.751 us; speedup 1.0000x reference)
//
#include <hip/hip_runtime.h>

#define BB 2
#define NN 16384
#define CC 64
#define SS 4096
#define KK 32
#define R2 0.16f   // RADIUS^2

// grid: 20 cells/dim, size 0.44 (> radius + fp margin), span [-4.4, 4.4] clamped
#define GD 20
#define NC (GD * GD * GD)     // 8000 cells per batch

typedef __bf16 bf16x8 __attribute__((ext_vector_type(8)));
typedef float  f32x4  __attribute__((ext_vector_type(4)));

#define MFMA(a, b, c) __builtin_amdgcn_mfma_f32_16x16x32_bf16((a), (b), (c), 0, 0, 0)

static __device__ __forceinline__ ushort f2bf(float f) {
    __bf16 h = (__bf16)f;
    return *(ushort*)&h;
}
static __device__ __forceinline__ int cellc(float x) {
    int v = (int)floorf((x + 4.4f) * 2.2727273f);
    return v < 0 ? 0 : (v > GD - 1 ? GD - 1 : v);
}

// workspace layout (bytes)
#define WS_PTS4   0          // 2*16384*16  = 524,288
#define WS_FEAT   524288     // 2*16384*64*2 = 4,194,304
#define WS_W1T    4718592    // 12,288
#define WS_W2T    4730880    // 8,192
#define WS_W3T    4739072    // 16,384
#define WS_CCNT   4755456    // 2*8000*4  = 64,000
#define WS_CSTART 4819456    // 2*8001*4  = 64,008 (+8 pad)
#define WS_CFILL  4883472    // 2*8000*4  = 64,000
#define WS_CPTS   4947472    // 2*16384*16 = 524,288
#define WS_CPIDX  5471760    // 2*16384*4  = 131,072  (end ~5.6 MB)

// prep index ranges
#define T_PTS   (BB * NN)                  // 32768
#define T_W1    (T_PTS + 64 * 96)
#define T_W2    (T_W1 + 64 * 64)
#define T_W3    (T_W2 + 128 * 64)
#define T_NXYZ  (T_W3 + BB * SS * 3)
#define T_SIDX  (T_NXYZ + BB * SS)
#define T_ALL   (T_SIDX + BB * NN)

// ---------------------------------------------------------------------------
// prep: pts4; cell histogram (atomicAdd, cell_cnt pre-zeroed by memset);
// bf16 weight transposes; new_xyz copy; samp_idx; feat transpose to bf16.
// ---------------------------------------------------------------------------
__global__ __launch_bounds__(256) void prep_kernel(
        const float* __restrict__ xyz, const float* __restrict__ feat,
        const float* __restrict__ W1, const float* __restrict__ W2,
        const float* __restrict__ W3,
        float4* __restrict__ pts4, ushort* __restrict__ feat_nc,
        ushort* __restrict__ W1t, ushort* __restrict__ W2t,
        ushort* __restrict__ W3t, int* __restrict__ cell_cnt,
        float* __restrict__ out_xyz, float* __restrict__ out_sidx) {
    const int t = blockIdx.x * 256 + threadIdx.x;
    if (t < T_PTS) {
        const float* p = xyz + (size_t)t * 3;
        const float x = p[0], y = p[1], z = p[2];
        pts4[t] = make_float4(x, y, z, x * x + y * y + z * z);
        const int cell = (cellc(z) * GD + cellc(y)) * GD + cellc(x);
        atomicAdd(&cell_cnt[(t >> 14) * NC + cell], 1);
    } else if (t < T_W1) {
        const int i = t - T_PTS;
        const int n = i / 96, k = i - n * 96;
        float v = 0.0f;
        if (k < 64) v = W1[(3 + k) * 64 + n];
        else if (k < 67) v = W1[(k - 64) * 64 + n];
        W1t[n * 96 + k] = f2bf(v);
    } else if (t < T_W2) {
        const int i = t - T_W1;
        const int n = i >> 6, k = i & 63;
        W2t[n * 64 + k] = f2bf(W2[k * 64 + n]);
    } else if (t < T_W3) {
        const int i = t - T_W2;
        const int n = i >> 6, k = i & 63;
        W3t[n * 64 + k] = f2bf(W3[k * 128 + n]);
    } else if (t < T_NXYZ) {
        const int i = t - T_W3;              // new_xyz = xyz[:, :SS] copy
        const int b = i / (SS * 3), j = i - b * (SS * 3);
        out_xyz[i] = xyz[(size_t)b * NN * 3 + j];
    } else if (t < T_SIDX) {
        const int i = t - T_NXYZ;
        out_sidx[i] = (float)(i & (SS - 1));
    } else if (t < T_ALL) {
        const int i = t - T_SIDX;            // 0 .. BB*NN-1
        const int b = i >> 14, n = i & (NN - 1);
        const float* fb = feat + (size_t)b * CC * NN + n;
        ushort* dst = feat_nc + (size_t)i * 64;
        #pragma unroll
        for (int c8 = 0; c8 < 8; ++c8) {
            uint u[4];
            #pragma unroll
            for (int j = 0; j < 4; ++j) {
                const float f0 = fb[(size_t)(c8 * 8 + 2 * j) * NN];
                const float f1 = fb[(size_t)(c8 * 8 + 2 * j + 1) * NN];
                u[j] = (uint)f2bf(f0) | ((uint)f2bf(f1) << 16);
            }
            *(uint4*)(dst + c8 * 8) = make_uint4(u[0], u[1], u[2], u[3]);
        }
    }
}

// ---------------------------------------------------------------------------
// scan_kernel: exclusive prefix sum of cell_cnt -> cell_start (+total at NC)
// and cell_fill (scatter cursors). One block per batch, chunked LDS scan.
// ---------------------------------------------------------------------------
__global__ __launch_bounds__(256) void scan_kernel(const int* __restrict__ cnt,
                                                   int* __restrict__ start,
                                                   int* __restrict__ fill) {
    const int b = blockIdx.x;
    const int* c = cnt + b * NC;
    int* st = start + b * (NC + 1);
    int* fl = fill + b * NC;
    const int tid = threadIdx.x;
    __shared__ int buf[256];
    __shared__ int sro;
    if (tid == 0) sro = 0;
    __syncthreads();
    for (int base = 0; base < NC; base += 256) {
        const int i = base + tid;
        const int v = (i < NC) ? c[i] : 0;
        const int ro = sro;
        buf[tid] = v;
        __syncthreads();
        for (int off = 1; off < 256; off <<= 1) {
            const int tv = (tid >= off) ? buf[tid - off] : 0;
            __syncthreads();
            buf[tid] += tv;
            __syncthreads();
        }
        const int excl = buf[tid] - v;
        const int tot = buf[255];
        if (i < NC) { st[i] = ro + excl; fl[i] = ro + excl; }
        __syncthreads();
        if (tid == 0) sro = ro + tot;
        __syncthreads();
    }
    if (tid == 0) st[NC] = sro;
}

// ---------------------------------------------------------------------------
// scatter_kernel: cell-ordered copies of (pts4, original index).
// ---------------------------------------------------------------------------
__global__ __launch_bounds__(256) void scatter_kernel(
        const float4* __restrict__ pts4, int* __restrict__ fill,
        float4* __restrict__ cpts, int* __restrict__ cpidx) {
    const int t = blockIdx.x * 256 + threadIdx.x;   // 0 .. 32767
    const float4 p = pts4[t];
    const int b = t >> 14, i = t & (NN - 1);
    const int cell = (cellc(p.z) * GD + cellc(p.y)) * GD + cellc(p.x);
    const int pos = atomicAdd(&fill[b * NC + cell], 1);
    cpts[(size_t)b * NN + pos] = p;
    cpidx[(size_t)b * NN + pos] = i;
}

// ---------------------------------------------------------------------------
// fused v3: GRID BALL QUERY (27 neighbor cells = 9 contiguous runs; ~850
// tests/centroid vs 8200 full-scan avg — R8..R12 showed the scan is bound
// by total tests, invariant to scheduling) + 32-smallest-index selection
// via wave-min extraction (output needs the SET of 32 smallest in-range
// indices: maxpool is order-invariant; pad = dup of min hit / 0 if none).
// MLP part unchanged from R11 (lockstep reverted).
// ---------------------------------------------------------------------------
__global__ __launch_bounds__(256, 2) void fused_kernel(
        const float4* __restrict__ pts4, const ushort* __restrict__ feat_nc,
        const int* __restrict__ cell_start, const float4* __restrict__ cpts,
        const int* __restrict__ cpidx,
        const ushort* __restrict__ W1t, const ushort* __restrict__ W2t,
        const ushort* __restrict__ W3t,
        const float* __restrict__ b1, const float* __restrict__ b2,
        const float* __restrict__ b3, float* __restrict__ out_feat) {
    const int w = threadIdx.x >> 6, lane = threadIdx.x & 63;
    const int quad = lane >> 4, mrow = lane & 15;
    const int m = lane & 31, half = lane >> 5;

    __shared__ __align__(16) ushort ldsA[4][32 * 104];   // cand -> g -> h1 -> h2
    __shared__ float stage[128][5];                      // [ch][4 s + pad]
    ushort* gbuf = ldsA[w];
    int* hit = (int*)gbuf;             // cand[0..511] during scan; hit[0..31] after

    const int xcd = blockIdx.x & 7;
    const int slot = blockIdx.x >> 3;              // 0..255
    const int b = xcd >> 2;
    const int s0 = ((xcd & 3) * 256 + slot) * 4;   // block's 4-s tile
    const int s = s0 + w;

    const float4* pb = pts4 + (size_t)b * NN;
    const ushort* fbase = feat_nc + (size_t)b * NN * 64;
    const unsigned long long ltmask = (1ull << lane) - 1ull;

    // ================= grid ball query =================
    {
        const float4 c = pb[s];
        const int cx = cellc(c.x), cy = cellc(c.y), cz = cellc(c.z);
        const int x0 = max(cx - 1, 0), x1 = min(cx + 1, GD - 1);
        const int y0 = max(cy - 1, 0), y1 = min(cy + 1, GD - 1);
        const int z0 = max(cz - 1, 0), z1 = min(cz + 1, GD - 1);
        const int* cs = cell_start + b * (NC + 1);
        const float4* cp = cpts + (size_t)b * NN;
        const int* ci = cpidx + (size_t)b * NN;

        int ccount = 0;
        for (int zz = z0; zz <= z1; ++zz) {
            for (int yy = y0; yy <= y1; ++yy) {
                const int rowbase = (zz * GD + yy) * GD;
                const int beg = cs[rowbase + x0];
                const int end = cs[rowbase + x1 + 1];
                for (int base = beg; base < end; base += 64) {
                    const int i = base + lane;
                    bool hf = false;
                    int pidx = 0;
                    if (i < end) {
                        const float4 p = cp[i];
                        const float d = c.w + p.w -
                            2.0f * (c.x * p.x + c.y * p.y + c.z * p.z);
                        hf = d < R2;
                        pidx = ci[i];
                    }
                    const unsigned long long mm = __ballot(hf);
                    if (hf) {
                        const int pos = ccount + (int)__popcll(mm & ltmask);
                        if (pos < 512) hit[pos] = pidx;
                    }
                    ccount += (int)__popcll(mm);
                }
            }
        }
        if (ccount > 512) ccount = 512;   // unreachable for this input (max ~360)

        // ---- select 32 smallest indices (wave-min extraction) --------------
        int vv[8];
        #pragma unroll
        for (int j = 0; j < 8; ++j)
            vv[j] = (lane + j * 64 < ccount) ? hit[lane + j * 64] : 0x7FFFFFFF;
        int mysid = 0x7FFFFFFF;
        int first = 0x7FFFFFFF;
        #pragma unroll 1
        for (int k = 0; k < KK; ++k) {
            int mn = vv[0];
            #pragma unroll
            for (int j = 1; j < 8; ++j) mn = min(mn, vv[j]);
            #pragma unroll
            for (int off = 1; off < 64; off <<= 1) mn = min(mn, __shfl_xor(mn, off));
            if (k == 0) first = mn;
            if (lane == k) mysid = mn;
            #pragma unroll
            for (int j = 0; j < 8; ++j) if (vv[j] == mn) vv[j] = 0x7FFFFFFF;
        }
        if (lane < KK) {
            int v;
            if (ccount == 0) v = 0;
            else v = (lane < ccount) ? mysid : first;
            hit[lane] = v;
        }
    }

    // ================= gather: sid (LDS) -> rows -> LDS =================
    {
        const int sid = hit[m];                  // wave-private, program order
        const ushort* src = fbase + (size_t)sid * 64 + half * 32;
        ushort* dst = gbuf + m * 104 + half * 32;
        uint4 rows[4];
        #pragma unroll
        for (int i = 0; i < 4; ++i) rows[i] = *(const uint4*)(src + i * 8);
        const float4 p = pb[sid];
        const float4 cc = pb[s];
        #pragma unroll
        for (int i = 0; i < 4; ++i) *(uint4*)(dst + i * 8) = rows[i];
        if (half == 0) {
            bf16x8 rel = {(__bf16)(p.x - cc.x), (__bf16)(p.y - cc.y),
                          (__bf16)(p.z - cc.z), (__bf16)0.f,
                          (__bf16)0.f, (__bf16)0.f, (__bf16)0.f, (__bf16)0.f};
            *(bf16x8*)(gbuf + m * 104 + 64) = rel;
            *(uint4*)(gbuf + m * 104 + 88) = make_uint4(0, 0, 0, 0);
        } else {
            *(uint4*)(gbuf + m * 104 + 72) = make_uint4(0, 0, 0, 0);
            *(uint4*)(gbuf + m * 104 + 80) = make_uint4(0, 0, 0, 0);
        }
    }

    // ================= layer 1: [32x96]x[96x64] =================
    {
        f32x4 acc[2][4];
        #pragma unroll
        for (int nt = 0; nt < 4; ++nt) {
            const float bv = b1[nt * 16 + mrow];
            acc[0][nt] = (f32x4){bv, bv, bv, bv};
            acc[1][nt] = acc[0][nt];
        }
        #pragma unroll
        for (int ks = 0; ks < 3; ++ks) {
            const bf16x8 a0 = *(const bf16x8*)(gbuf + mrow * 104 + ks * 32 + quad * 8);
            const bf16x8 a1 = *(const bf16x8*)(gbuf + (16 + mrow) * 104 + ks * 32 + quad * 8);
            #pragma unroll
            for (int nt = 0; nt < 4; ++nt) {
                const bf16x8 wf = *(const bf16x8*)(W1t + (nt * 16 + mrow) * 96 + ks * 32 + quad * 8);
                acc[0][nt] = MFMA(a0, wf, acc[0][nt]);
                acc[1][nt] = MFMA(a1, wf, acc[1][nt]);
            }
        }
        #pragma unroll
        for (int mt = 0; mt < 2; ++mt)
            #pragma unroll
            for (int nt = 0; nt < 4; ++nt)
                #pragma unroll
                for (int r = 0; r < 4; ++r)
                    gbuf[(mt * 16 + quad * 4 + r) * 104 + nt * 16 + mrow] =
                        f2bf(fmaxf(acc[mt][nt][r], 0.0f));
    }

    // ================= layer 2: [32x64]x[64x64] =================
    {
        f32x4 acc[2][4];
        #pragma unroll
        for (int nt = 0; nt < 4; ++nt) {
            const float bv = b2[nt * 16 + mrow];
            acc[0][nt] = (f32x4){bv, bv, bv, bv};
            acc[1][nt] = acc[0][nt];
        }
        #pragma unroll
        for (int ks = 0; ks < 2; ++ks) {
            const bf16x8 a0 = *(const bf16x8*)(gbuf + mrow * 104 + ks * 32 + quad * 8);
            const bf16x8 a1 = *(const bf16x8*)(gbuf + (16 + mrow) * 104 + ks * 32 + quad * 8);
            #pragma unroll
            for (int nt = 0; nt < 4; ++nt) {
                const bf16x8 wf = *(const bf16x8*)(W2t + (nt * 16 + mrow) * 64 + ks * 32 + quad * 8);
                acc[0][nt] = MFMA(a0, wf, acc[0][nt]);
                acc[1][nt] = MFMA(a1, wf, acc[1][nt]);
            }
        }
        #pragma unroll
        for (int mt = 0; mt < 2; ++mt)
            #pragma unroll
            for (int nt = 0; nt < 4; ++nt)
                #pragma unroll
                for (int r = 0; r < 4; ++r)
                    gbuf[(mt * 16 + quad * 4 + r) * 104 + nt * 16 + mrow] =
                        f2bf(fmaxf(acc[mt][nt][r], 0.0f));
    }

    // ============ layer 3: [32x64]x[64x128] two n-halves + maxpool ==========
    #pragma unroll
    for (int nh = 0; nh < 2; ++nh) {
        f32x4 acc[2][4];
        #pragma unroll
        for (int ntl = 0; ntl < 4; ++ntl) {
            const float bv = b3[(nh * 4 + ntl) * 16 + mrow];
            acc[0][ntl] = (f32x4){bv, bv, bv, bv};
            acc[1][ntl] = acc[0][ntl];
        }
        #pragma unroll
        for (int ks = 0; ks < 2; ++ks) {
            const bf16x8 a0 = *(const bf16x8*)(gbuf + mrow * 104 + ks * 32 + quad * 8);
            const bf16x8 a1 = *(const bf16x8*)(gbuf + (16 + mrow) * 104 + ks * 32 + quad * 8);
            #pragma unroll
            for (int ntl = 0; ntl < 4; ++ntl) {
                const bf16x8 wf = *(const bf16x8*)(
                    W3t + ((nh * 4 + ntl) * 16 + mrow) * 64 + ks * 32 + quad * 8);
                acc[0][ntl] = MFMA(a0, wf, acc[0][ntl]);
                acc[1][ntl] = MFMA(a1, wf, acc[1][ntl]);
            }
        }
        #pragma unroll
        for (int ntl = 0; ntl < 4; ++ntl) {
            const f32x4 v0 = acc[0][ntl], v1 = acc[1][ntl];
            float mx = fmaxf(fmaxf(v0[0], v0[1]), fmaxf(v0[2], v0[3]));
            mx = fmaxf(mx, fmaxf(fmaxf(v1[0], v1[1]), fmaxf(v1[2], v1[3])));
            mx = fmaxf(mx, __shfl_xor(mx, 16));
            mx = fmaxf(mx, __shfl_xor(mx, 32));
            mx = fmaxf(mx, 0.0f);
            if (quad == 0) stage[(nh * 4 + ntl) * 16 + mrow][w] = mx;
        }
    }
    __syncthreads();

    // ---- epilogue: 128 ch x 4 s, float2 per thread -------------------------
    {
        const int ch = threadIdx.x & 127;
        const int hf = threadIdx.x >> 7;           // 0/1
        float* dst = out_feat + ((size_t)b * 128 + ch) * SS + s0 + hf * 2;
        *(float2*)dst = make_float2(stage[ch][hf * 2], stage[ch][hf * 2 + 1]);
    }
}

// ---------------------------------------------------------------------------
extern "C" void kernel_launch(void* const* d_in, const int* in_sizes, int n_in,
                              void* d_out, int out_size, void* d_ws, size_t ws_size,
                              hipStream_t stream) {
    const float* xyz  = (const float*)d_in[0];
    const float* feat = (const float*)d_in[1];
    const float* W1   = (const float*)d_in[2];
    const float* b1   = (const float*)d_in[3];
    const float* W2   = (const float*)d_in[4];
    const float* b2   = (const float*)d_in[5];
    const float* W3   = (const float*)d_in[6];
    const float* b3   = (const float*)d_in[7];

    float* out      = (float*)d_out;
    float* out_xyz  = out;                               // [2,4096,3]
    float* out_feat = out + (size_t)BB * SS * 3;         // [2,128,4096]
    float* out_sidx = out_feat + (size_t)BB * 128 * SS;  // [2,4096]

    char* ws = (char*)d_ws;
    float4* pts4    = (float4*)(ws + WS_PTS4);
    ushort* feat_nc = (ushort*)(ws + WS_FEAT);
    ushort* W1t     = (ushort*)(ws + WS_W1T);
    ushort* W2t     = (ushort*)(ws + WS_W2T);
    ushort* W3t     = (ushort*)(ws + WS_W3T);
    int*    ccnt    = (int*)(ws + WS_CCNT);
    int*    cstart  = (int*)(ws + WS_CSTART);
    int*    cfill   = (int*)(ws + WS_CFILL);
    float4* cpts    = (float4*)(ws + WS_CPTS);
    int*    cpidx   = (int*)(ws + WS_CPIDX);

    hipMemsetAsync(ccnt, 0, BB * NC * sizeof(int), stream);
    prep_kernel<<<(T_ALL + 255) / 256, 256, 0, stream>>>(
        xyz, feat, W1, W2, W3, pts4, feat_nc, W1t, W2t, W3t, ccnt,
        out_xyz, out_sidx);
    scan_kernel<<<BB, 256, 0, stream>>>(ccnt, cstart, cfill);
    scatter_kernel<<<BB * NN / 256, 256, 0, stream>>>(pts4, cfill, cpts, cpidx);
    fused_kernel<<<BB * SS / 4, 256, 0, stream>>>(
        pts4, feat_nc, cstart, cpts, cpidx, W1t, W2t, W3t, b1, b2, b3, out_feat);
}

// Round 14
// 185.048 us; speedup vs baseline: 1.0686x; 1.0686x over previous
//
#include <hip/hip_runtime.h>

#define BB 2
#define NN 16384
#define CC 64
#define SS 4096
#define KK 32
#define R2 0.16f   // RADIUS^2

// grid: 20 cells/dim, size 0.44 (> radius + fp margin), span [-4.4, 4.4] clamped
#define GD 20
#define NC (GD * GD * GD)     // 8000 cells per batch

typedef __bf16 bf16x8 __attribute__((ext_vector_type(8)));
typedef float  f32x4  __attribute__((ext_vector_type(4)));

#define MFMA(a, b, c) __builtin_amdgcn_mfma_f32_16x16x32_bf16((a), (b), (c), 0, 0, 0)

static __device__ __forceinline__ ushort f2bf(float f) {
    __bf16 h = (__bf16)f;
    return *(ushort*)&h;
}
static __device__ __forceinline__ int cellc(float x) {
    int v = (int)floorf((x + 4.4f) * 2.2727273f);
    return v < 0 ? 0 : (v > GD - 1 ? GD - 1 : v);
}

// workspace layout (bytes)
#define WS_PTS4   0          // 2*16384*16   = 524,288
#define WS_FEAT   524288     // 2*16384*64*2 = 4,194,304
#define WS_W1T    4718592    // 12,288
#define WS_W2T    4730880    // 8,192
#define WS_W3T    4739072    // 16,384
#define WS_CSTART 4755456    // 2*8001*4 = 64,008 (+pad)
#define WS_CID    4819472    // 2*16384*4 = 131,072
#define WS_CPTS   4950544    // 2*16384*16 = 524,288 (16B aligned)
#define WS_CPIDX  5474832    // 2*16384*4 = 131,072  (end ~5.6 MB)

// prep index ranges
#define T_PTS   (BB * NN)                  // 32768
#define T_W1    (T_PTS + 64 * 96)
#define T_W2    (T_W1 + 64 * 64)
#define T_W3    (T_W2 + 128 * 64)
#define T_NXYZ  (T_W3 + BB * SS * 3)
#define T_SIDX  (T_NXYZ + BB * SS)
#define T_ALL   (T_SIDX + BB * NN)

// ---------------------------------------------------------------------------
// prep: pts4 + cellid (no atomics); bf16 weight transposes; new_xyz copy;
// samp_idx; feat transpose to bf16.
// ---------------------------------------------------------------------------
__global__ __launch_bounds__(256) void prep_kernel(
        const float* __restrict__ xyz, const float* __restrict__ feat,
        const float* __restrict__ W1, const float* __restrict__ W2,
        const float* __restrict__ W3,
        float4* __restrict__ pts4, ushort* __restrict__ feat_nc,
        ushort* __restrict__ W1t, ushort* __restrict__ W2t,
        ushort* __restrict__ W3t, int* __restrict__ cellid,
        float* __restrict__ out_xyz, float* __restrict__ out_sidx) {
    const int t = blockIdx.x * 256 + threadIdx.x;
    if (t < T_PTS) {
        const float* p = xyz + (size_t)t * 3;
        const float x = p[0], y = p[1], z = p[2];
        pts4[t] = make_float4(x, y, z, x * x + y * y + z * z);
        cellid[t] = (cellc(z) * GD + cellc(y)) * GD + cellc(x);
    } else if (t < T_W1) {
        const int i = t - T_PTS;
        const int n = i / 96, k = i - n * 96;
        float v = 0.0f;
        if (k < 64) v = W1[(3 + k) * 64 + n];
        else if (k < 67) v = W1[(k - 64) * 64 + n];
        W1t[n * 96 + k] = f2bf(v);
    } else if (t < T_W2) {
        const int i = t - T_W1;
        const int n = i >> 6, k = i & 63;
        W2t[n * 64 + k] = f2bf(W2[k * 64 + n]);
    } else if (t < T_W3) {
        const int i = t - T_W2;
        const int n = i >> 6, k = i & 63;
        W3t[n * 64 + k] = f2bf(W3[k * 128 + n]);
    } else if (t < T_NXYZ) {
        const int i = t - T_W3;              // new_xyz = xyz[:, :SS] copy
        const int b = i / (SS * 3), j = i - b * (SS * 3);
        out_xyz[i] = xyz[(size_t)b * NN * 3 + j];
    } else if (t < T_SIDX) {
        const int i = t - T_NXYZ;
        out_sidx[i] = (float)(i & (SS - 1));
    } else if (t < T_ALL) {
        const int i = t - T_SIDX;            // 0 .. BB*NN-1
        const int b = i >> 14, n = i & (NN - 1);
        const float* fb = feat + (size_t)b * CC * NN + n;
        ushort* dst = feat_nc + (size_t)i * 64;
        #pragma unroll
        for (int c8 = 0; c8 < 8; ++c8) {
            uint u[4];
            #pragma unroll
            for (int j = 0; j < 4; ++j) {
                const float f0 = fb[(size_t)(c8 * 8 + 2 * j) * NN];
                const float f1 = fb[(size_t)(c8 * 8 + 2 * j + 1) * NN];
                u[j] = (uint)f2bf(f0) | ((uint)f2bf(f1) << 16);
            }
            *(uint4*)(dst + c8 * 8) = make_uint4(u[0], u[1], u[2], u[3]);
        }
    }
}

// ---------------------------------------------------------------------------
// bin_kernel: one block per batch. LDS histogram from cellids -> single-pass
// LDS scan (8 cells/thread local + 1024-wide Hillis-Steele, ~20 barriers vs
// R13's 512) -> write cell_start -> scatter with LDS cursors. Replaces
// memset + scan_kernel + scatter_kernel (5 dispatches -> 3).
// ---------------------------------------------------------------------------
__global__ __launch_bounds__(1024) void bin_kernel(
        const float4* __restrict__ pts4, const int* __restrict__ cellid,
        int* __restrict__ cell_start, float4* __restrict__ cpts,
        int* __restrict__ cpidx) {
    const int b = blockIdx.x;
    const int tid = threadIdx.x;
    __shared__ int cnt[NC];       // hist -> scanned starts -> scatter cursors
    __shared__ int buf[1024];

    for (int i = tid; i < NC; i += 1024) cnt[i] = 0;
    __syncthreads();

    const int* cid = cellid + b * NN;
    for (int i = tid; i < NN; i += 1024) atomicAdd(&cnt[cid[i]], 1);
    __syncthreads();

    // local scan over this thread's 8 cells
    int loc[8];
    int sum = 0;
    #pragma unroll
    for (int j = 0; j < 8; ++j) {
        const int i = tid * 8 + j;
        loc[j] = sum;
        sum += (i < NC) ? cnt[i] : 0;
    }
    buf[tid] = sum;
    __syncthreads();
    // Hillis-Steele inclusive scan over 1024 partials
    for (int off = 1; off < 1024; off <<= 1) {
        const int v = (tid >= off) ? buf[tid - off] : 0;
        __syncthreads();
        buf[tid] += v;
        __syncthreads();
    }
    const int excl = buf[tid] - sum;
    __syncthreads();                       // cnt still being read above? no — safe
    #pragma unroll
    for (int j = 0; j < 8; ++j) {
        const int i = tid * 8 + j;
        if (i < NC) {
            const int st = excl + loc[j];
            cell_start[b * (NC + 1) + i] = st;
            cnt[i] = st;                   // becomes scatter cursor
        }
    }
    if (tid == 0) cell_start[b * (NC + 1) + NC] = NN;
    __syncthreads();

    // scatter (order within cell arbitrary — selection handles it)
    const float4* pb = pts4 + (size_t)b * NN;
    for (int i = tid; i < NN; i += 1024) {
        const int pos = atomicAdd(&cnt[cid[i]], 1);
        cpts[(size_t)b * NN + pos] = pb[i];
        cpidx[(size_t)b * NN + pos] = i;
    }
}

// ---------------------------------------------------------------------------
// fused v3 (unchanged from R13): grid ball query (27 cells = 9 runs) +
// smallest-32-index selection via wave-min extraction + MLP + maxpool.
// ---------------------------------------------------------------------------
__global__ __launch_bounds__(256, 2) void fused_kernel(
        const float4* __restrict__ pts4, const ushort* __restrict__ feat_nc,
        const int* __restrict__ cell_start, const float4* __restrict__ cpts,
        const int* __restrict__ cpidx,
        const ushort* __restrict__ W1t, const ushort* __restrict__ W2t,
        const ushort* __restrict__ W3t,
        const float* __restrict__ b1, const float* __restrict__ b2,
        const float* __restrict__ b3, float* __restrict__ out_feat) {
    const int w = threadIdx.x >> 6, lane = threadIdx.x & 63;
    const int quad = lane >> 4, mrow = lane & 15;
    const int m = lane & 31, half = lane >> 5;

    __shared__ __align__(16) ushort ldsA[4][32 * 104];   // cand -> g -> h1 -> h2
    __shared__ float stage[128][5];                      // [ch][4 s + pad]
    ushort* gbuf = ldsA[w];
    int* hit = (int*)gbuf;             // cand[0..511] during scan; hit[0..31] after

    const int xcd = blockIdx.x & 7;
    const int slot = blockIdx.x >> 3;              // 0..255
    const int b = xcd >> 2;
    const int s0 = ((xcd & 3) * 256 + slot) * 4;   // block's 4-s tile
    const int s = s0 + w;

    const float4* pb = pts4 + (size_t)b * NN;
    const ushort* fbase = feat_nc + (size_t)b * NN * 64;
    const unsigned long long ltmask = (1ull << lane) - 1ull;

    // ================= grid ball query =================
    {
        const float4 c = pb[s];
        const int cx = cellc(c.x), cy = cellc(c.y), cz = cellc(c.z);
        const int x0 = max(cx - 1, 0), x1 = min(cx + 1, GD - 1);
        const int y0 = max(cy - 1, 0), y1 = min(cy + 1, GD - 1);
        const int z0 = max(cz - 1, 0), z1 = min(cz + 1, GD - 1);
        const int* cs = cell_start + b * (NC + 1);
        const float4* cp = cpts + (size_t)b * NN;
        const int* ci = cpidx + (size_t)b * NN;

        int ccount = 0;
        for (int zz = z0; zz <= z1; ++zz) {
            for (int yy = y0; yy <= y1; ++yy) {
                const int rowbase = (zz * GD + yy) * GD;
                const int beg = cs[rowbase + x0];
                const int end = cs[rowbase + x1 + 1];
                for (int base = beg; base < end; base += 64) {
                    const int i = base + lane;
                    bool hf = false;
                    int pidx = 0;
                    if (i < end) {
                        const float4 p = cp[i];
                        const float d = c.w + p.w -
                            2.0f * (c.x * p.x + c.y * p.y + c.z * p.z);
                        hf = d < R2;
                        pidx = ci[i];
                    }
                    const unsigned long long mm = __ballot(hf);
                    if (hf) {
                        const int pos = ccount + (int)__popcll(mm & ltmask);
                        if (pos < 512) hit[pos] = pidx;
                    }
                    ccount += (int)__popcll(mm);
                }
            }
        }
        if (ccount > 512) ccount = 512;   // unreachable for this input (max ~360)

        // ---- select 32 smallest indices (wave-min extraction) --------------
        int vv[8];
        #pragma unroll
        for (int j = 0; j < 8; ++j)
            vv[j] = (lane + j * 64 < ccount) ? hit[lane + j * 64] : 0x7FFFFFFF;
        int mysid = 0x7FFFFFFF;
        int first = 0x7FFFFFFF;
        #pragma unroll 1
        for (int k = 0; k < KK; ++k) {
            int mn = vv[0];
            #pragma unroll
            for (int j = 1; j < 8; ++j) mn = min(mn, vv[j]);
            #pragma unroll
            for (int off = 1; off < 64; off <<= 1) mn = min(mn, __shfl_xor(mn, off));
            if (k == 0) first = mn;
            if (lane == k) mysid = mn;
            #pragma unroll
            for (int j = 0; j < 8; ++j) if (vv[j] == mn) vv[j] = 0x7FFFFFFF;
        }
        if (lane < KK) {
            int v;
            if (ccount == 0) v = 0;
            else v = (lane < ccount) ? mysid : first;
            hit[lane] = v;
        }
    }

    // ================= gather: sid (LDS) -> rows -> LDS =================
    {
        const int sid = hit[m];                  // wave-private, program order
        const ushort* src = fbase + (size_t)sid * 64 + half * 32;
        ushort* dst = gbuf + m * 104 + half * 32;
        uint4 rows[4];
        #pragma unroll
        for (int i = 0; i < 4; ++i) rows[i] = *(const uint4*)(src + i * 8);
        const float4 p = pb[sid];
        const float4 cc = pb[s];
        #pragma unroll
        for (int i = 0; i < 4; ++i) *(uint4*)(dst + i * 8) = rows[i];
        if (half == 0) {
            bf16x8 rel = {(__bf16)(p.x - cc.x), (__bf16)(p.y - cc.y),
                          (__bf16)(p.z - cc.z), (__bf16)0.f,
                          (__bf16)0.f, (__bf16)0.f, (__bf16)0.f, (__bf16)0.f};
            *(bf16x8*)(gbuf + m * 104 + 64) = rel;
            *(uint4*)(gbuf + m * 104 + 88) = make_uint4(0, 0, 0, 0);
        } else {
            *(uint4*)(gbuf + m * 104 + 72) = make_uint4(0, 0, 0, 0);
            *(uint4*)(gbuf + m * 104 + 80) = make_uint4(0, 0, 0, 0);
        }
    }

    // ================= layer 1: [32x96]x[96x64] =================
    {
        f32x4 acc[2][4];
        #pragma unroll
        for (int nt = 0; nt < 4; ++nt) {
            const float bv = b1[nt * 16 + mrow];
            acc[0][nt] = (f32x4){bv, bv, bv, bv};
            acc[1][nt] = acc[0][nt];
        }
        #pragma unroll
        for (int ks = 0; ks < 3; ++ks) {
            const bf16x8 a0 = *(const bf16x8*)(gbuf + mrow * 104 + ks * 32 + quad * 8);
            const bf16x8 a1 = *(const bf16x8*)(gbuf + (16 + mrow) * 104 + ks * 32 + quad * 8);
            #pragma unroll
            for (int nt = 0; nt < 4; ++nt) {
                const bf16x8 wf = *(const bf16x8*)(W1t + (nt * 16 + mrow) * 96 + ks * 32 + quad * 8);
                acc[0][nt] = MFMA(a0, wf, acc[0][nt]);
                acc[1][nt] = MFMA(a1, wf, acc[1][nt]);
            }
        }
        #pragma unroll
        for (int mt = 0; mt < 2; ++mt)
            #pragma unroll
            for (int nt = 0; nt < 4; ++nt)
                #pragma unroll
                for (int r = 0; r < 4; ++r)
                    gbuf[(mt * 16 + quad * 4 + r) * 104 + nt * 16 + mrow] =
                        f2bf(fmaxf(acc[mt][nt][r], 0.0f));
    }

    // ================= layer 2: [32x64]x[64x64] =================
    {
        f32x4 acc[2][4];
        #pragma unroll
        for (int nt = 0; nt < 4; ++nt) {
            const float bv = b2[nt * 16 + mrow];
            acc[0][nt] = (f32x4){bv, bv, bv, bv};
            acc[1][nt] = acc[0][nt];
        }
        #pragma unroll
        for (int ks = 0; ks < 2; ++ks) {
            const bf16x8 a0 = *(const bf16x8*)(gbuf + mrow * 104 + ks * 32 + quad * 8);
            const bf16x8 a1 = *(const bf16x8*)(gbuf + (16 + mrow) * 104 + ks * 32 + quad * 8);
            #pragma unroll
            for (int nt = 0; nt < 4; ++nt) {
                const bf16x8 wf = *(const bf16x8*)(W2t + (nt * 16 + mrow) * 64 + ks * 32 + quad * 8);
                acc[0][nt] = MFMA(a0, wf, acc[0][nt]);
                acc[1][nt] = MFMA(a1, wf, acc[1][nt]);
            }
        }
        #pragma unroll
        for (int mt = 0; mt < 2; ++mt)
            #pragma unroll
            for (int nt = 0; nt < 4; ++nt)
                #pragma unroll
                for (int r = 0; r < 4; ++r)
                    gbuf[(mt * 16 + quad * 4 + r) * 104 + nt * 16 + mrow] =
                        f2bf(fmaxf(acc[mt][nt][r], 0.0f));
    }

    // ============ layer 3: [32x64]x[64x128] two n-halves + maxpool ==========
    #pragma unroll
    for (int nh = 0; nh < 2; ++nh) {
        f32x4 acc[2][4];
        #pragma unroll
        for (int ntl = 0; ntl < 4; ++ntl) {
            const float bv = b3[(nh * 4 + ntl) * 16 + mrow];
            acc[0][ntl] = (f32x4){bv, bv, bv, bv};
            acc[1][ntl] = acc[0][ntl];
        }
        #pragma unroll
        for (int ks = 0; ks < 2; ++ks) {
            const bf16x8 a0 = *(const bf16x8*)(gbuf + mrow * 104 + ks * 32 + quad * 8);
            const bf16x8 a1 = *(const bf16x8*)(gbuf + (16 + mrow) * 104 + ks * 32 + quad * 8);
            #pragma unroll
            for (int ntl = 0; ntl < 4; ++ntl) {
                const bf16x8 wf = *(const bf16x8*)(
                    W3t + ((nh * 4 + ntl) * 16 + mrow) * 64 + ks * 32 + quad * 8);
                acc[0][ntl] = MFMA(a0, wf, acc[0][ntl]);
                acc[1][ntl] = MFMA(a1, wf, acc[1][ntl]);
            }
        }
        #pragma unroll
        for (int ntl = 0; ntl < 4; ++ntl) {
            const f32x4 v0 = acc[0][ntl], v1 = acc[1][ntl];
            float mx = fmaxf(fmaxf(v0[0], v0[1]), fmaxf(v0[2], v0[3]));
            mx = fmaxf(mx, fmaxf(fmaxf(v1[0], v1[1]), fmaxf(v1[2], v1[3])));
            mx = fmaxf(mx, __shfl_xor(mx, 16));
            mx = fmaxf(mx, __shfl_xor(mx, 32));
            mx = fmaxf(mx, 0.0f);
            if (quad == 0) stage[(nh * 4 + ntl) * 16 + mrow][w] = mx;
        }
    }
    __syncthreads();

    // ---- epilogue: 128 ch x 4 s, float2 per thread -------------------------
    {
        const int ch = threadIdx.x & 127;
        const int hf = threadIdx.x >> 7;           // 0/1
        float* dst = out_feat + ((size_t)b * 128 + ch) * SS + s0 + hf * 2;
        *(float2*)dst = make_float2(stage[ch][hf * 2], stage[ch][hf * 2 + 1]);
    }
}

// ---------------------------------------------------------------------------
extern "C" void kernel_launch(void* const* d_in, const int* in_sizes, int n_in,
                              void* d_out, int out_size, void* d_ws, size_t ws_size,
                              hipStream_t stream) {
    const float* xyz  = (const float*)d_in[0];
    const float* feat = (const float*)d_in[1];
    const float* W1   = (const float*)d_in[2];
    const float* b1   = (const float*)d_in[3];
    const float* W2   = (const float*)d_in[4];
    const float* b2   = (const float*)d_in[5];
    const float* W3   = (const float*)d_in[6];
    const float* b3   = (const float*)d_in[7];

    float* out      = (float*)d_out;
    float* out_xyz  = out;                               // [2,4096,3]
    float* out_feat = out + (size_t)BB * SS * 3;         // [2,128,4096]
    float* out_sidx = out_feat + (size_t)BB * 128 * SS;  // [2,4096]

    char* ws = (char*)d_ws;
    float4* pts4    = (float4*)(ws + WS_PTS4);
    ushort* feat_nc = (ushort*)(ws + WS_FEAT);
    ushort* W1t     = (ushort*)(ws + WS_W1T);
    ushort* W2t     = (ushort*)(ws + WS_W2T);
    ushort* W3t     = (ushort*)(ws + WS_W3T);
    int*    cstart  = (int*)(ws + WS_CSTART);
    int*    cid     = (int*)(ws + WS_CID);
    float4* cpts    = (float4*)(ws + WS_CPTS);
    int*    cpidx   = (int*)(ws + WS_CPIDX);

    prep_kernel<<<(T_ALL + 255) / 256, 256, 0, stream>>>(
        xyz, feat, W1, W2, W3, pts4, feat_nc, W1t, W2t, W3t, cid,
        out_xyz, out_sidx);
    bin_kernel<<<BB, 1024, 0, stream>>>(pts4, cid, cstart, cpts, cpidx);
    fused_kernel<<<BB * SS / 4, 256, 0, stream>>>(
        pts4, feat_nc, cstart, cpts, cpidx, W1t, W2t, W3t, b1, b2, b3, out_feat);
}

// Round 15
// 169.970 us; speedup vs baseline: 1.1634x; 1.0887x over previous
//
#include <hip/hip_runtime.h>

#define BB 2
#define NN 16384
#define CC 64
#define SS 4096
#define KK 32
#define R2 0.16f   // RADIUS^2

// grid: 20 cells/dim, size 0.44 (> radius + fp margin), span [-4.4, 4.4] clamped
#define GD 20
#define NC (GD * GD * GD)     // 8000 cells per batch

typedef __bf16 bf16x8 __attribute__((ext_vector_type(8)));
typedef float  f32x4  __attribute__((ext_vector_type(4)));

#define MFMA(a, b, c) __builtin_amdgcn_mfma_f32_16x16x32_bf16((a), (b), (c), 0, 0, 0)

static __device__ __forceinline__ ushort f2bf(float f) {
    __bf16 h = (__bf16)f;
    return *(ushort*)&h;
}
static __device__ __forceinline__ int cellc(float x) {
    int v = (int)floorf((x + 4.4f) * 2.2727273f);
    return v < 0 ? 0 : (v > GD - 1 ? GD - 1 : v);
}

// workspace layout (bytes)
#define WS_PTS4   0          // 2*16384*16   = 524,288
#define WS_FEAT   524288     // 2*16384*64*2 = 4,194,304
#define WS_W1T    4718592    // 12,288
#define WS_W2T    4730880    // 8,192
#define WS_W3T    4739072    // 16,384
#define WS_CCNT   4755456    // 2*8000*4 = 64,000
#define WS_CSTART 4819456    // 2*8001*4 = 64,008
#define WS_CFILL  4883472    // 2*8000*4 = 64,000
#define WS_CPTS   4947472    // 2*16384*16 = 524,288
#define WS_CPIDX  5471760    // 2*16384*4 = 131,072   (end ~5.6 MB)

// prep index ranges
#define T_PTS   (BB * NN)                  // 32768
#define T_W1    (T_PTS + 64 * 96)
#define T_W2    (T_W1 + 64 * 64)
#define T_W3    (T_W2 + 128 * 64)
#define T_NXYZ  (T_W3 + BB * SS * 3)
#define T_SIDX  (T_NXYZ + BB * SS)
#define T_ALL   (T_SIDX + BB * NN)

// ---------------------------------------------------------------------------
// prep: pts4 + global-atomic cell histogram (ccnt memset-zeroed); bf16 weight
// transposes; new_xyz copy; samp_idx; feat transpose to bf16.
// ---------------------------------------------------------------------------
__global__ __launch_bounds__(256) void prep_kernel(
        const float* __restrict__ xyz, const float* __restrict__ feat,
        const float* __restrict__ W1, const float* __restrict__ W2,
        const float* __restrict__ W3,
        float4* __restrict__ pts4, ushort* __restrict__ feat_nc,
        ushort* __restrict__ W1t, ushort* __restrict__ W2t,
        ushort* __restrict__ W3t, int* __restrict__ cell_cnt,
        float* __restrict__ out_xyz, float* __restrict__ out_sidx) {
    const int t = blockIdx.x * 256 + threadIdx.x;
    if (t < T_PTS) {
        const float* p = xyz + (size_t)t * 3;
        const float x = p[0], y = p[1], z = p[2];
        pts4[t] = make_float4(x, y, z, x * x + y * y + z * z);
        const int cell = (cellc(z) * GD + cellc(y)) * GD + cellc(x);
        atomicAdd(&cell_cnt[(t >> 14) * NC + cell], 1);
    } else if (t < T_W1) {
        const int i = t - T_PTS;
        const int n = i / 96, k = i - n * 96;
        float v = 0.0f;
        if (k < 64) v = W1[(3 + k) * 64 + n];
        else if (k < 67) v = W1[(k - 64) * 64 + n];
        W1t[n * 96 + k] = f2bf(v);
    } else if (t < T_W2) {
        const int i = t - T_W1;
        const int n = i >> 6, k = i & 63;
        W2t[n * 64 + k] = f2bf(W2[k * 64 + n]);
    } else if (t < T_W3) {
        const int i = t - T_W2;
        const int n = i >> 6, k = i & 63;
        W3t[n * 64 + k] = f2bf(W3[k * 128 + n]);
    } else if (t < T_NXYZ) {
        const int i = t - T_W3;              // new_xyz = xyz[:, :SS] copy
        const int b = i / (SS * 3), j = i - b * (SS * 3);
        out_xyz[i] = xyz[(size_t)b * NN * 3 + j];
    } else if (t < T_SIDX) {
        const int i = t - T_NXYZ;
        out_sidx[i] = (float)(i & (SS - 1));
    } else if (t < T_ALL) {
        const int i = t - T_SIDX;            // 0 .. BB*NN-1
        const int b = i >> 14, n = i & (NN - 1);
        const float* fb = feat + (size_t)b * CC * NN + n;
        ushort* dst = feat_nc + (size_t)i * 64;
        #pragma unroll
        for (int c8 = 0; c8 < 8; ++c8) {
            uint u[4];
            #pragma unroll
            for (int j = 0; j < 4; ++j) {
                const float f0 = fb[(size_t)(c8 * 8 + 2 * j) * NN];
                const float f1 = fb[(size_t)(c8 * 8 + 2 * j + 1) * NN];
                u[j] = (uint)f2bf(f0) | ((uint)f2bf(f1) << 16);
            }
            *(uint4*)(dst + c8 * 8) = make_uint4(u[0], u[1], u[2], u[3]);
        }
    }
}

// ---------------------------------------------------------------------------
// scan_kernel: one 1024-thread block per batch; 8 cells/thread local scan +
// single 1024-wide Hillis-Steele = ~20 barriers (R13's 512-barrier version
// measured ~50us; this is the fix). Writes cell_start and cell_fill.
// ---------------------------------------------------------------------------
__global__ __launch_bounds__(1024) void scan_kernel(const int* __restrict__ cnt,
                                                    int* __restrict__ start,
                                                    int* __restrict__ fill) {
    const int b = blockIdx.x;
    const int* c = cnt + b * NC;
    int* st = start + b * (NC + 1);
    int* fl = fill + b * NC;
    const int tid = threadIdx.x;
    __shared__ int buf[1024];
    int loc[8];
    int sum = 0;
    #pragma unroll
    for (int j = 0; j < 8; ++j) {
        const int i = tid * 8 + j;
        loc[j] = sum;
        sum += (i < NC) ? c[i] : 0;
    }
    buf[tid] = sum;
    __syncthreads();
    for (int off = 1; off < 1024; off <<= 1) {
        const int v = (tid >= off) ? buf[tid - off] : 0;
        __syncthreads();
        buf[tid] += v;
        __syncthreads();
    }
    const int excl = buf[tid] - sum;
    #pragma unroll
    for (int j = 0; j < 8; ++j) {
        const int i = tid * 8 + j;
        if (i < NC) {
            const int s0 = excl + loc[j];
            st[i] = s0;
            fl[i] = s0;
        }
    }
    if (tid == 0) st[NC] = NN;
}

// ---------------------------------------------------------------------------
// scatter_kernel: WIDE (128 blocks) — cell-ordered copies of (pts4, index).
// (R14's 2-block bin did this on 2 CUs: ~27us of write-allocate on one L2
// port. Width is the fix.)
// ---------------------------------------------------------------------------
__global__ __launch_bounds__(256) void scatter_kernel(
        const float4* __restrict__ pts4, int* __restrict__ fill,
        float4* __restrict__ cpts, int* __restrict__ cpidx) {
    const int t = blockIdx.x * 256 + threadIdx.x;   // 0 .. 32767
    const float4 p = pts4[t];
    const int b = t >> 14, i = t & (NN - 1);
    const int cell = (cellc(p.z) * GD + cellc(p.y)) * GD + cellc(p.x);
    const int pos = atomicAdd(&fill[b * NC + cell], 1);
    cpts[(size_t)b * NN + pos] = p;
    cpidx[(size_t)b * NN + pos] = i;
}

// ---------------------------------------------------------------------------
// fused v4: grid ball query with LDS run-table + 1-deep cross-run prefetch
// (R14's loop issued dependent cp/ci loads per chunk — the dominant stall),
// threshold-select of the 32 smallest indices (14-iter binary search over
// unique 14-bit indices; replaces 32-round serial extraction), then the
// unchanged MLP + maxpool + staged epilogue.
// ---------------------------------------------------------------------------
__global__ __launch_bounds__(256, 2) void fused_kernel(
        const float4* __restrict__ pts4, const ushort* __restrict__ feat_nc,
        const int* __restrict__ cell_start, const float4* __restrict__ cpts,
        const int* __restrict__ cpidx,
        const ushort* __restrict__ W1t, const ushort* __restrict__ W2t,
        const ushort* __restrict__ W3t,
        const float* __restrict__ b1, const float* __restrict__ b2,
        const float* __restrict__ b3, float* __restrict__ out_feat) {
    const int w = threadIdx.x >> 6, lane = threadIdx.x & 63;
    const int quad = lane >> 4, mrow = lane & 15;
    const int m = lane & 31, half = lane >> 5;

    __shared__ __align__(16) ushort ldsA[4][32 * 104];   // cand+runs -> g -> h1 -> h2
    __shared__ float stage[128][5];                      // [ch][4 s + pad]
    ushort* gbuf = ldsA[w];
    int* hit = (int*)gbuf;             // cand[0..511]; runs at [544..561]; hit[0..31] after
    int* runs = hit + 544;

    const int xcd = blockIdx.x & 7;
    const int slot = blockIdx.x >> 3;              // 0..255
    const int b = xcd >> 2;
    const int s0 = ((xcd & 3) * 256 + slot) * 4;   // block's 4-s tile
    const int s = s0 + w;

    const float4* pb = pts4 + (size_t)b * NN;
    const ushort* fbase = feat_nc + (size_t)b * NN * 64;
    const unsigned long long ltmask = (1ull << lane) - 1ull;

    // ================= grid ball query =================
    {
        const float4 c = pb[s];
        const int cx = cellc(c.x), cy = cellc(c.y), cz = cellc(c.z);
        const int x0 = max(cx - 1, 0), x1 = min(cx + 1, GD - 1);
        const int y0 = max(cy - 1, 0), y1 = min(cy + 1, GD - 1);
        const int z0 = max(cz - 1, 0), z1 = min(cz + 1, GD - 1);
        const int* cs = cell_start + b * (NC + 1);
        const float4* cp = cpts + (size_t)b * NN;
        const int* ci = cpidx + (size_t)b * NN;

        // build run table (<=9 contiguous [beg,end) spans) in LDS
        int nr = 0;
        for (int zz = z0; zz <= z1; ++zz) {
            for (int yy = y0; yy <= y1; ++yy) {
                const int rowbase = (zz * GD + yy) * GD;
                const int bgn = cs[rowbase + x0];
                const int end = cs[rowbase + x1 + 1];
                if (bgn < end) {
                    if (lane == 0) { runs[2 * nr] = bgn; runs[2 * nr + 1] = end; }
                    ++nr;
                }
            }
        }

        int ccount = 0;
        if (nr > 0) {
            int r = 0;
            int base = runs[0], curEnd = runs[1];
            int i0 = base + lane;
            bool vld = i0 < curEnd;
            float4 pc;
            int pidx = 0;
            if (vld) { pc = cp[i0]; pidx = ci[i0]; }
            for (;;) {
                // compute next chunk position (possibly next run)
                int rn = r, nbase = base + 64, nEnd = curEnd;
                if (nbase >= curEnd) {
                    rn = r + 1;
                    if (rn < nr) { nbase = runs[2 * rn]; nEnd = runs[2 * rn + 1]; }
                }
                const bool haveNext = rn < nr;
                // prefetch next chunk (independent of current's test)
                float4 pn;
                int pnidx = 0;
                bool nvld = false;
                if (haveNext) {
                    const int ni = nbase + lane;
                    nvld = ni < nEnd;
                    if (nvld) { pn = cp[ni]; pnidx = ci[ni]; }
                }
                // test current chunk
                bool hf = false;
                if (vld) {
                    const float d = c.w + pc.w -
                        2.0f * (c.x * pc.x + c.y * pc.y + c.z * pc.z);
                    hf = d < R2;
                }
                const unsigned long long mm = __ballot(hf);
                if (hf) {
                    const int pos = ccount + (int)__popcll(mm & ltmask);
                    if (pos < 512) hit[pos] = pidx;
                }
                ccount += (int)__popcll(mm);
                if (!haveNext) break;
                r = rn; base = nbase; curEnd = nEnd;
                vld = nvld; pc = pn; pidx = pnidx;
            }
        }
        if (ccount > 512) ccount = 512;   // unreachable for this input (max ~360)

        // ---- select the 32 smallest indices: binary-search threshold -------
        int vv[8];
        #pragma unroll
        for (int j = 0; j < 8; ++j) {
            const int i = lane + j * 64;
            vv[j] = (i < ccount) ? hit[i] : 0x7FFFFFFF;
        }
        if (ccount > 0) {
            const int nkeep = (ccount < KK) ? ccount : KK;
            int lo = 0, hi = 16384;          // indices are unique, 14-bit
            while (hi - lo > 1) {            // 14 wave-uniform iterations
                const int mid = (lo + hi) >> 1;
                int cb = 0;
                #pragma unroll
                for (int j = 0; j < 8; ++j) cb += (vv[j] < mid) ? 1 : 0;
                #pragma unroll
                for (int off = 1; off < 64; off <<= 1) cb += __shfl_xor(cb, off);
                if (cb >= nkeep) hi = mid; else lo = mid;
            }
            const int T = hi;                // exactly nkeep values are < T
            int mn = vv[0];
            #pragma unroll
            for (int j = 1; j < 8; ++j) mn = min(mn, vv[j]);
            #pragma unroll
            for (int off = 1; off < 64; off <<= 1) mn = min(mn, __shfl_xor(mn, off));
            int cum = 0;
            #pragma unroll
            for (int j = 0; j < 8; ++j) {
                const bool pred = vv[j] < T;
                const unsigned long long mk = __ballot(pred);
                if (pred) hit[cum + (int)__popcll(mk & ltmask)] = vv[j];
                cum += (int)__popcll(mk);
            }
            if (lane >= nkeep && lane < KK) hit[lane] = mn;   // pad = min hit
        } else {
            if (lane < KK) hit[lane] = 0;
        }
    }

    // ================= gather: sid (LDS) -> rows -> LDS =================
    {
        const int sid = hit[m];                  // wave-private, program order
        const ushort* src = fbase + (size_t)sid * 64 + half * 32;
        ushort* dst = gbuf + m * 104 + half * 32;
        uint4 rows[4];
        #pragma unroll
        for (int i = 0; i < 4; ++i) rows[i] = *(const uint4*)(src + i * 8);
        const float4 p = pb[sid];
        const float4 cc = pb[s];
        #pragma unroll
        for (int i = 0; i < 4; ++i) *(uint4*)(dst + i * 8) = rows[i];
        if (half == 0) {
            bf16x8 rel = {(__bf16)(p.x - cc.x), (__bf16)(p.y - cc.y),
                          (__bf16)(p.z - cc.z), (__bf16)0.f,
                          (__bf16)0.f, (__bf16)0.f, (__bf16)0.f, (__bf16)0.f};
            *(bf16x8*)(gbuf + m * 104 + 64) = rel;
            *(uint4*)(gbuf + m * 104 + 88) = make_uint4(0, 0, 0, 0);
        } else {
            *(uint4*)(gbuf + m * 104 + 72) = make_uint4(0, 0, 0, 0);
            *(uint4*)(gbuf + m * 104 + 80) = make_uint4(0, 0, 0, 0);
        }
    }

    // ================= layer 1: [32x96]x[96x64] =================
    {
        f32x4 acc[2][4];
        #pragma unroll
        for (int nt = 0; nt < 4; ++nt) {
            const float bv = b1[nt * 16 + mrow];
            acc[0][nt] = (f32x4){bv, bv, bv, bv};
            acc[1][nt] = acc[0][nt];
        }
        #pragma unroll
        for (int ks = 0; ks < 3; ++ks) {
            const bf16x8 a0 = *(const bf16x8*)(gbuf + mrow * 104 + ks * 32 + quad * 8);
            const bf16x8 a1 = *(const bf16x8*)(gbuf + (16 + mrow) * 104 + ks * 32 + quad * 8);
            #pragma unroll
            for (int nt = 0; nt < 4; ++nt) {
                const bf16x8 wf = *(const bf16x8*)(W1t + (nt * 16 + mrow) * 96 + ks * 32 + quad * 8);
                acc[0][nt] = MFMA(a0, wf, acc[0][nt]);
                acc[1][nt] = MFMA(a1, wf, acc[1][nt]);
            }
        }
        #pragma unroll
        for (int mt = 0; mt < 2; ++mt)
            #pragma unroll
            for (int nt = 0; nt < 4; ++nt)
                #pragma unroll
                for (int r = 0; r < 4; ++r)
                    gbuf[(mt * 16 + quad * 4 + r) * 104 + nt * 16 + mrow] =
                        f2bf(fmaxf(acc[mt][nt][r], 0.0f));
    }

    // ================= layer 2: [32x64]x[64x64] =================
    {
        f32x4 acc[2][4];
        #pragma unroll
        for (int nt = 0; nt < 4; ++nt) {
            const float bv = b2[nt * 16 + mrow];
            acc[0][nt] = (f32x4){bv, bv, bv, bv};
            acc[1][nt] = acc[0][nt];
        }
        #pragma unroll
        for (int ks = 0; ks < 2; ++ks) {
            const bf16x8 a0 = *(const bf16x8*)(gbuf + mrow * 104 + ks * 32 + quad * 8);
            const bf16x8 a1 = *(const bf16x8*)(gbuf + (16 + mrow) * 104 + ks * 32 + quad * 8);
            #pragma unroll
            for (int nt = 0; nt < 4; ++nt) {
                const bf16x8 wf = *(const bf16x8*)(W2t + (nt * 16 + mrow) * 64 + ks * 32 + quad * 8);
                acc[0][nt] = MFMA(a0, wf, acc[0][nt]);
                acc[1][nt] = MFMA(a1, wf, acc[1][nt]);
            }
        }
        #pragma unroll
        for (int mt = 0; mt < 2; ++mt)
            #pragma unroll
            for (int nt = 0; nt < 4; ++nt)
                #pragma unroll
                for (int r = 0; r < 4; ++r)
                    gbuf[(mt * 16 + quad * 4 + r) * 104 + nt * 16 + mrow] =
                        f2bf(fmaxf(acc[mt][nt][r], 0.0f));
    }

    // ============ layer 3: [32x64]x[64x128] two n-halves + maxpool ==========
    #pragma unroll
    for (int nh = 0; nh < 2; ++nh) {
        f32x4 acc[2][4];
        #pragma unroll
        for (int ntl = 0; ntl < 4; ++ntl) {
            const float bv = b3[(nh * 4 + ntl) * 16 + mrow];
            acc[0][ntl] = (f32x4){bv, bv, bv, bv};
            acc[1][ntl] = acc[0][ntl];
        }
        #pragma unroll
        for (int ks = 0; ks < 2; ++ks) {
            const bf16x8 a0 = *(const bf16x8*)(gbuf + mrow * 104 + ks * 32 + quad * 8);
            const bf16x8 a1 = *(const bf16x8*)(gbuf + (16 + mrow) * 104 + ks * 32 + quad * 8);
            #pragma unroll
            for (int ntl = 0; ntl < 4; ++ntl) {
                const bf16x8 wf = *(const bf16x8*)(
                    W3t + ((nh * 4 + ntl) * 16 + mrow) * 64 + ks * 32 + quad * 8);
                acc[0][ntl] = MFMA(a0, wf, acc[0][ntl]);
                acc[1][ntl] = MFMA(a1, wf, acc[1][ntl]);
            }
        }
        #pragma unroll
        for (int ntl = 0; ntl < 4; ++ntl) {
            const f32x4 v0 = acc[0][ntl], v1 = acc[1][ntl];
            float mx = fmaxf(fmaxf(v0[0], v0[1]), fmaxf(v0[2], v0[3]));
            mx = fmaxf(mx, fmaxf(fmaxf(v1[0], v1[1]), fmaxf(v1[2], v1[3])));
            mx = fmaxf(mx, __shfl_xor(mx, 16));
            mx = fmaxf(mx, __shfl_xor(mx, 32));
            mx = fmaxf(mx, 0.0f);
            if (quad == 0) stage[(nh * 4 + ntl) * 16 + mrow][w] = mx;
        }
    }
    __syncthreads();

    // ---- epilogue: 128 ch x 4 s, float2 per thread -------------------------
    {
        const int ch = threadIdx.x & 127;
        const int hf = threadIdx.x >> 7;           // 0/1
        float* dst = out_feat + ((size_t)b * 128 + ch) * SS + s0 + hf * 2;
        *(float2*)dst = make_float2(stage[ch][hf * 2], stage[ch][hf * 2 + 1]);
    }
}

// ---------------------------------------------------------------------------
extern "C" void kernel_launch(void* const* d_in, const int* in_sizes, int n_in,
                              void* d_out, int out_size, void* d_ws, size_t ws_size,
                              hipStream_t stream) {
    const float* xyz  = (const float*)d_in[0];
    const float* feat = (const float*)d_in[1];
    const float* W1   = (const float*)d_in[2];
    const float* b1   = (const float*)d_in[3];
    const float* W2   = (const float*)d_in[4];
    const float* b2   = (const float*)d_in[5];
    const float* W3   = (const float*)d_in[6];
    const float* b3   = (const float*)d_in[7];

    float* out      = (float*)d_out;
    float* out_xyz  = out;                               // [2,4096,3]
    float* out_feat = out + (size_t)BB * SS * 3;         // [2,128,4096]
    float* out_sidx = out_feat + (size_t)BB * 128 * SS;  // [2,4096]

    char* ws = (char*)d_ws;
    float4* pts4    = (float4*)(ws + WS_PTS4);
    ushort* feat_nc = (ushort*)(ws + WS_FEAT);
    ushort* W1t     = (ushort*)(ws + WS_W1T);
    ushort* W2t     = (ushort*)(ws + WS_W2T);
    ushort* W3t     = (ushort*)(ws + WS_W3T);
    int*    ccnt    = (int*)(ws + WS_CCNT);
    int*    cstart  = (int*)(ws + WS_CSTART);
    int*    cfill   = (int*)(ws + WS_CFILL);
    float4* cpts    = (float4*)(ws + WS_CPTS);
    int*    cpidx   = (int*)(ws + WS_CPIDX);

    hipMemsetAsync(ccnt, 0, BB * NC * sizeof(int), stream);
    prep_kernel<<<(T_ALL + 255) / 256, 256, 0, stream>>>(
        xyz, feat, W1, W2, W3, pts4, feat_nc, W1t, W2t, W3t, ccnt,
        out_xyz, out_sidx);
    scan_kernel<<<BB, 1024, 0, stream>>>(ccnt, cstart, cfill);
    scatter_kernel<<<BB * NN / 256, 256, 0, stream>>>(pts4, cfill, cpts, cpidx);
    fused_kernel<<<BB * SS / 4, 256, 0, stream>>>(
        pts4, feat_nc, cstart, cpts, cpidx, W1t, W2t, W3t, b1, b2, b3, out_feat);
}

// Round 16
// 160.596 us; speedup vs baseline: 1.2314x; 1.0584x over previous
//
#include <hip/hip_runtime.h>

#define BB 2
#define NN 16384
#define CC 64
#define SS 4096
#define KK 32
#define R2 0.16f   // RADIUS^2

// grid: 20 cells/dim, size 0.44 (> radius + fp margin), span [-4.4, 4.4] clamped
#define GD 20
#define NC (GD * GD * GD)     // 8000 cells per batch

typedef __bf16 bf16x8 __attribute__((ext_vector_type(8)));
typedef float  f32x4  __attribute__((ext_vector_type(4)));

#define MFMA(a, b, c) __builtin_amdgcn_mfma_f32_16x16x32_bf16((a), (b), (c), 0, 0, 0)

static __device__ __forceinline__ ushort f2bf(float f) {
    __bf16 h = (__bf16)f;
    return *(ushort*)&h;
}
static __device__ __forceinline__ int cellc(float x) {
    int v = (int)floorf((x + 4.4f) * 2.2727273f);
    return v < 0 ? 0 : (v > GD - 1 ? GD - 1 : v);
}

// workspace layout (bytes)
#define WS_PTS4   0          // 2*16384*16   = 524,288
#define WS_FEAT   524288     // 2*16384*64*2 = 4,194,304
#define WS_W1T    4718592    // 12,288
#define WS_W2T    4730880    // 8,192
#define WS_W3T    4739072    // 16,384
#define WS_CSTART 4755456    // 2*8001*4 = 64,008 (+pad)
#define WS_CFILL  4819472    // 2*8000*4 = 64,000
#define WS_CID    4883472    // 2*16384*4 = 131,072
#define WS_CPTS   5014544    // 2*16384*16 = 524,288 (16B aligned)
#define WS_CPIDX  5538832    // 2*16384*4 = 131,072   (end ~5.67 MB)

// prep index ranges
#define T_PTS   (BB * NN)                  // 32768
#define T_W1    (T_PTS + 64 * 96)
#define T_W2    (T_W1 + 64 * 64)
#define T_W3    (T_W2 + 128 * 64)
#define T_NXYZ  (T_W3 + BB * SS * 3)
#define T_SIDX  (T_NXYZ + BB * SS)
#define T_ALL   (T_SIDX + BB * NN)

// ---------------------------------------------------------------------------
// prep: pts4 + cellid (no atomics, no memset dependency); bf16 weight
// transposes; new_xyz copy; samp_idx; feat transpose to bf16.
// ---------------------------------------------------------------------------
__global__ __launch_bounds__(256) void prep_kernel(
        const float* __restrict__ xyz, const float* __restrict__ feat,
        const float* __restrict__ W1, const float* __restrict__ W2,
        const float* __restrict__ W3,
        float4* __restrict__ pts4, ushort* __restrict__ feat_nc,
        ushort* __restrict__ W1t, ushort* __restrict__ W2t,
        ushort* __restrict__ W3t, int* __restrict__ cellid,
        float* __restrict__ out_xyz, float* __restrict__ out_sidx) {
    const int t = blockIdx.x * 256 + threadIdx.x;
    if (t < T_PTS) {
        const float* p = xyz + (size_t)t * 3;
        const float x = p[0], y = p[1], z = p[2];
        pts4[t] = make_float4(x, y, z, x * x + y * y + z * z);
        cellid[t] = (cellc(z) * GD + cellc(y)) * GD + cellc(x);
    } else if (t < T_W1) {
        const int i = t - T_PTS;
        const int n = i / 96, k = i - n * 96;
        float v = 0.0f;
        if (k < 64) v = W1[(3 + k) * 64 + n];
        else if (k < 67) v = W1[(k - 64) * 64 + n];
        W1t[n * 96 + k] = f2bf(v);
    } else if (t < T_W2) {
        const int i = t - T_W1;
        const int n = i >> 6, k = i & 63;
        W2t[n * 64 + k] = f2bf(W2[k * 64 + n]);
    } else if (t < T_W3) {
        const int i = t - T_W2;
        const int n = i >> 6, k = i & 63;
        W3t[n * 64 + k] = f2bf(W3[k * 128 + n]);
    } else if (t < T_NXYZ) {
        const int i = t - T_W3;              // new_xyz = xyz[:, :SS] copy
        const int b = i / (SS * 3), j = i - b * (SS * 3);
        out_xyz[i] = xyz[(size_t)b * NN * 3 + j];
    } else if (t < T_SIDX) {
        const int i = t - T_NXYZ;
        out_sidx[i] = (float)(i & (SS - 1));
    } else if (t < T_ALL) {
        const int i = t - T_SIDX;            // 0 .. BB*NN-1
        const int b = i >> 14, n = i & (NN - 1);
        const float* fb = feat + (size_t)b * CC * NN + n;
        ushort* dst = feat_nc + (size_t)i * 64;
        #pragma unroll
        for (int c8 = 0; c8 < 8; ++c8) {
            uint u[4];
            #pragma unroll
            for (int j = 0; j < 4; ++j) {
                const float f0 = fb[(size_t)(c8 * 8 + 2 * j) * NN];
                const float f1 = fb[(size_t)(c8 * 8 + 2 * j + 1) * NN];
                u[j] = (uint)f2bf(f0) | ((uint)f2bf(f1) << 16);
            }
            *(uint4*)(dst + c8 * 8) = make_uint4(u[0], u[1], u[2], u[3]);
        }
    }
}

// ---------------------------------------------------------------------------
// histscan: one 1024-thread block per batch. LDS histogram from cellid ->
// 8 cells/thread local scan + one 1024-wide Hillis-Steele (~20 barriers).
// Replaces memset + global-atomic hist + scan (two fewer dispatches).
// ---------------------------------------------------------------------------
__global__ __launch_bounds__(1024) void histscan_kernel(
        const int* __restrict__ cellid, int* __restrict__ start,
        int* __restrict__ fill) {
    const int b = blockIdx.x;
    const int tid = threadIdx.x;
    __shared__ int cnt[NC];
    __shared__ int buf[1024];
    for (int i = tid; i < NC; i += 1024) cnt[i] = 0;
    __syncthreads();
    const int* cid = cellid + b * NN;
    for (int i = tid; i < NN; i += 1024) atomicAdd(&cnt[cid[i]], 1);
    __syncthreads();
    int loc[8];
    int sum = 0;
    #pragma unroll
    for (int j = 0; j < 8; ++j) {
        const int i = tid * 8 + j;
        loc[j] = sum;
        sum += (i < NC) ? cnt[i] : 0;
    }
    buf[tid] = sum;
    __syncthreads();
    for (int off = 1; off < 1024; off <<= 1) {
        const int v = (tid >= off) ? buf[tid - off] : 0;
        __syncthreads();
        buf[tid] += v;
        __syncthreads();
    }
    const int excl = buf[tid] - sum;
    int* st = start + b * (NC + 1);
    int* fl = fill + b * NC;
    #pragma unroll
    for (int j = 0; j < 8; ++j) {
        const int i = tid * 8 + j;
        if (i < NC) {
            const int s0 = excl + loc[j];
            st[i] = s0;
            fl[i] = s0;
        }
    }
    if (tid == 0) st[NC] = NN;
}

// ---------------------------------------------------------------------------
// scatter: WIDE (128 blocks) — cell-ordered copies of (pts4, index).
// ---------------------------------------------------------------------------
__global__ __launch_bounds__(256) void scatter_kernel(
        const float4* __restrict__ pts4, const int* __restrict__ cellid,
        int* __restrict__ fill, float4* __restrict__ cpts,
        int* __restrict__ cpidx) {
    const int t = blockIdx.x * 256 + threadIdx.x;   // 0 .. 32767
    const int b = t >> 14, i = t & (NN - 1);
    const int cell = cellid[t];
    const int pos = atomicAdd(&fill[b * NC + cell], 1);
    cpts[(size_t)b * NN + pos] = pts4[t];
    cpidx[(size_t)b * NN + pos] = i;
}

// ---------------------------------------------------------------------------
// fused v5: 128-thread blocks (2 waves; LDS 14KB -> ~11 blocks/CU = 22
// waves/CU vs R15's 12) + FLATTENED query: run table built lane-parallel
// (9 rows loaded concurrently, wave prefix-sum, shfl broadcast -> one
// latency instead of 18 serial loads), candidate space iterated flat with
// position-only addresses (1-deep rotating prefetch, loads independent of
// hit bookkeeping). Selection + MLP unchanged from R15.
// ---------------------------------------------------------------------------
__global__ __launch_bounds__(128, 4) void fused_kernel(
        const float4* __restrict__ pts4, const ushort* __restrict__ feat_nc,
        const int* __restrict__ cell_start, const float4* __restrict__ cpts,
        const int* __restrict__ cpidx,
        const ushort* __restrict__ W1t, const ushort* __restrict__ W2t,
        const ushort* __restrict__ W3t,
        const float* __restrict__ b1, const float* __restrict__ b2,
        const float* __restrict__ b3, float* __restrict__ out_feat) {
    const int w = threadIdx.x >> 6, lane = threadIdx.x & 63;
    const int quad = lane >> 4, mrow = lane & 15;
    const int m = lane & 31, half = lane >> 5;

    __shared__ __align__(16) ushort ldsA[2][32 * 104];   // cand -> g -> h1 -> h2
    __shared__ float stage[128][2];                      // [ch][2 s]
    ushort* gbuf = ldsA[w];
    int* hit = (int*)gbuf;             // cand[0..511] during scan; hit[0..31] after

    const int xcd = blockIdx.x & 7;
    const int slot = blockIdx.x >> 3;              // 0..511
    const int b = xcd >> 2;
    const int s0 = ((xcd & 3) * 512 + slot) * 2;   // block's 2-s tile
    const int s = s0 + w;

    const float4* pb = pts4 + (size_t)b * NN;
    const ushort* fbase = feat_nc + (size_t)b * NN * 64;
    const unsigned long long ltmask = (1ull << lane) - 1ull;

    // ================= flattened grid ball query =================
    {
        const float4 c = pb[s];
        const int cx = cellc(c.x), cy = cellc(c.y), cz = cellc(c.z);
        const int x0 = max(cx - 1, 0), x1 = min(cx + 1, GD - 1);
        const int y0 = max(cy - 1, 0), y1 = min(cy + 1, GD - 1);
        const int z0 = max(cz - 1, 0), z1 = min(cz + 1, GD - 1);
        const int ny = y1 - y0 + 1;
        const int nrows = ny * (z1 - z0 + 1);      // <= 9
        const int* cs = cell_start + b * (NC + 1);
        const float4* cp = cpts + (size_t)b * NN;
        const int* ci = cpidx + (size_t)b * NN;

        // lane-parallel run table: lane r < nrows loads row r's [beg,end)
        int beg = 0, len = 0;
        if (lane < nrows) {
            const int zz = z0 + lane / ny;
            const int yy = y0 + lane - (lane / ny) * ny;
            const int rowbase = (zz * GD + yy) * GD;
            beg = cs[rowbase + x0];
            len = cs[rowbase + x1 + 1] - beg;
        }
        // wave prefix-sum of len -> flattened offsets
        int pre = len;
        #pragma unroll
        for (int off = 1; off < 64; off <<= 1) {
            const int v = __shfl_up(pre, off);
            if (lane >= off) pre += v;
        }
        const int excl = pre - len;
        const int total = __shfl(pre, 63);
        // broadcast per-run (flat offset, addr bias) into registers
        int aj[9], bjr[9];
        #pragma unroll
        for (int j = 0; j < 9; ++j) {
            aj[j] = __shfl(excl, j);
            bjr[j] = __shfl(beg, j) - aj[j];
        }

        int ccount = 0;
        {
            // prologue: position lane
            int base = 0;
            bool vld = lane < total;
            float4 pc;
            int pidx = 0;
            if (vld) {
                int ad = bjr[0] + lane;
                #pragma unroll
                for (int j = 1; j < 9; ++j)
                    if (j < nrows && lane >= aj[j]) ad = bjr[j] + lane;
                pc = cp[ad];
                pidx = ci[ad];
            }
            for (;;) {
                const int nbase = base + 64;
                // prefetch next chunk (addresses independent of bookkeeping)
                float4 pn;
                int pnidx = 0;
                const int npos = nbase + lane;
                const bool nvld = npos < total;
                if (nvld) {
                    int ad = bjr[0] + npos;
                    #pragma unroll
                    for (int j = 1; j < 9; ++j)
                        if (j < nrows && npos >= aj[j]) ad = bjr[j] + npos;
                    pn = cp[ad];
                    pnidx = ci[ad];
                }
                // test current chunk
                bool hf = false;
                if (vld) {
                    const float d = c.w + pc.w -
                        2.0f * (c.x * pc.x + c.y * pc.y + c.z * pc.z);
                    hf = d < R2;
                }
                const unsigned long long mm = __ballot(hf);
                if (hf) {
                    const int p = ccount + (int)__popcll(mm & ltmask);
                    if (p < 512) hit[p] = pidx;
                }
                ccount += (int)__popcll(mm);
                if (nbase >= total) break;
                base = nbase;
                vld = nvld; pc = pn; pidx = pnidx;
            }
        }
        if (ccount > 512) ccount = 512;

        // ---- select the 32 smallest indices: binary-search threshold -------
        int vv[8];
        #pragma unroll
        for (int j = 0; j < 8; ++j) {
            const int i = lane + j * 64;
            vv[j] = (i < ccount) ? hit[i] : 0x7FFFFFFF;
        }
        if (ccount > 0) {
            const int nkeep = (ccount < KK) ? ccount : KK;
            int lo = 0, hi = 16384;          // indices unique, 14-bit
            while (hi - lo > 1) {
                const int mid = (lo + hi) >> 1;
                int cb = 0;
                #pragma unroll
                for (int j = 0; j < 8; ++j) cb += (vv[j] < mid) ? 1 : 0;
                #pragma unroll
                for (int off = 1; off < 64; off <<= 1) cb += __shfl_xor(cb, off);
                if (cb >= nkeep) hi = mid; else lo = mid;
            }
            const int T = hi;                // exactly nkeep values < T
            int mn = vv[0];
            #pragma unroll
            for (int j = 1; j < 8; ++j) mn = min(mn, vv[j]);
            #pragma unroll
            for (int off = 1; off < 64; off <<= 1) mn = min(mn, __shfl_xor(mn, off));
            int cum = 0;
            #pragma unroll
            for (int j = 0; j < 8; ++j) {
                const bool pred = vv[j] < T;
                const unsigned long long mk = __ballot(pred);
                if (pred) hit[cum + (int)__popcll(mk & ltmask)] = vv[j];
                cum += (int)__popcll(mk);
            }
            if (lane >= nkeep && lane < KK) hit[lane] = mn;   // pad = min hit
        } else {
            if (lane < KK) hit[lane] = 0;
        }
    }

    // ================= gather: sid (LDS) -> rows -> LDS =================
    {
        const int sid = hit[m];                  // wave-private, program order
        const ushort* src = fbase + (size_t)sid * 64 + half * 32;
        ushort* dst = gbuf + m * 104 + half * 32;
        uint4 rows[4];
        #pragma unroll
        for (int i = 0; i < 4; ++i) rows[i] = *(const uint4*)(src + i * 8);
        const float4 p = pb[sid];
        const float4 cc = pb[s];
        #pragma unroll
        for (int i = 0; i < 4; ++i) *(uint4*)(dst + i * 8) = rows[i];
        if (half == 0) {
            bf16x8 rel = {(__bf16)(p.x - cc.x), (__bf16)(p.y - cc.y),
                          (__bf16)(p.z - cc.z), (__bf16)0.f,
                          (__bf16)0.f, (__bf16)0.f, (__bf16)0.f, (__bf16)0.f};
            *(bf16x8*)(gbuf + m * 104 + 64) = rel;
            *(uint4*)(gbuf + m * 104 + 88) = make_uint4(0, 0, 0, 0);
        } else {
            *(uint4*)(gbuf + m * 104 + 72) = make_uint4(0, 0, 0, 0);
            *(uint4*)(gbuf + m * 104 + 80) = make_uint4(0, 0, 0, 0);
        }
    }

    // ================= layer 1: [32x96]x[96x64] =================
    {
        f32x4 acc[2][4];
        #pragma unroll
        for (int nt = 0; nt < 4; ++nt) {
            const float bv = b1[nt * 16 + mrow];
            acc[0][nt] = (f32x4){bv, bv, bv, bv};
            acc[1][nt] = acc[0][nt];
        }
        #pragma unroll
        for (int ks = 0; ks < 3; ++ks) {
            const bf16x8 a0 = *(const bf16x8*)(gbuf + mrow * 104 + ks * 32 + quad * 8);
            const bf16x8 a1 = *(const bf16x8*)(gbuf + (16 + mrow) * 104 + ks * 32 + quad * 8);
            #pragma unroll
            for (int nt = 0; nt < 4; ++nt) {
                const bf16x8 wf = *(const bf16x8*)(W1t + (nt * 16 + mrow) * 96 + ks * 32 + quad * 8);
                acc[0][nt] = MFMA(a0, wf, acc[0][nt]);
                acc[1][nt] = MFMA(a1, wf, acc[1][nt]);
            }
        }
        #pragma unroll
        for (int mt = 0; mt < 2; ++mt)
            #pragma unroll
            for (int nt = 0; nt < 4; ++nt)
                #pragma unroll
                for (int r = 0; r < 4; ++r)
                    gbuf[(mt * 16 + quad * 4 + r) * 104 + nt * 16 + mrow] =
                        f2bf(fmaxf(acc[mt][nt][r], 0.0f));
    }

    // ================= layer 2: [32x64]x[64x64] =================
    {
        f32x4 acc[2][4];
        #pragma unroll
        for (int nt = 0; nt < 4; ++nt) {
            const float bv = b2[nt * 16 + mrow];
            acc[0][nt] = (f32x4){bv, bv, bv, bv};
            acc[1][nt] = acc[0][nt];
        }
        #pragma unroll
        for (int ks = 0; ks < 2; ++ks) {
            const bf16x8 a0 = *(const bf16x8*)(gbuf + mrow * 104 + ks * 32 + quad * 8);
            const bf16x8 a1 = *(const bf16x8*)(gbuf + (16 + mrow) * 104 + ks * 32 + quad * 8);
            #pragma unroll
            for (int nt = 0; nt < 4; ++nt) {
                const bf16x8 wf = *(const bf16x8*)(W2t + (nt * 16 + mrow) * 64 + ks * 32 + quad * 8);
                acc[0][nt] = MFMA(a0, wf, acc[0][nt]);
                acc[1][nt] = MFMA(a1, wf, acc[1][nt]);
            }
        }
        #pragma unroll
        for (int mt = 0; mt < 2; ++mt)
            #pragma unroll
            for (int nt = 0; nt < 4; ++nt)
                #pragma unroll
                for (int r = 0; r < 4; ++r)
                    gbuf[(mt * 16 + quad * 4 + r) * 104 + nt * 16 + mrow] =
                        f2bf(fmaxf(acc[mt][nt][r], 0.0f));
    }

    // ============ layer 3: [32x64]x[64x128] two n-halves + maxpool ==========
    #pragma unroll
    for (int nh = 0; nh < 2; ++nh) {
        f32x4 acc[2][4];
        #pragma unroll
        for (int ntl = 0; ntl < 4; ++ntl) {
            const float bv = b3[(nh * 4 + ntl) * 16 + mrow];
            acc[0][ntl] = (f32x4){bv, bv, bv, bv};
            acc[1][ntl] = acc[0][ntl];
        }
        #pragma unroll
        for (int ks = 0; ks < 2; ++ks) {
            const bf16x8 a0 = *(const bf16x8*)(gbuf + mrow * 104 + ks * 32 + quad * 8);
            const bf16x8 a1 = *(const bf16x8*)(gbuf + (16 + mrow) * 104 + ks * 32 + quad * 8);
            #pragma unroll
            for (int ntl = 0; ntl < 4; ++ntl) {
                const bf16x8 wf = *(const bf16x8*)(
                    W3t + ((nh * 4 + ntl) * 16 + mrow) * 64 + ks * 32 + quad * 8);
                acc[0][ntl] = MFMA(a0, wf, acc[0][ntl]);
                acc[1][ntl] = MFMA(a1, wf, acc[1][ntl]);
            }
        }
        #pragma unroll
        for (int ntl = 0; ntl < 4; ++ntl) {
            const f32x4 v0 = acc[0][ntl], v1 = acc[1][ntl];
            float mx = fmaxf(fmaxf(v0[0], v0[1]), fmaxf(v0[2], v0[3]));
            mx = fmaxf(mx, fmaxf(fmaxf(v1[0], v1[1]), fmaxf(v1[2], v1[3])));
            mx = fmaxf(mx, __shfl_xor(mx, 16));
            mx = fmaxf(mx, __shfl_xor(mx, 32));
            mx = fmaxf(mx, 0.0f);
            if (quad == 0) stage[(nh * 4 + ntl) * 16 + mrow][w] = mx;
        }
    }
    __syncthreads();

    // ---- epilogue: 128 ch x 2 s, float2 per thread -------------------------
    {
        const int ch = threadIdx.x;                // 0..127
        float* dst = out_feat + ((size_t)b * 128 + ch) * SS + s0;
        *(float2*)dst = make_float2(stage[ch][0], stage[ch][1]);
    }
}

// ---------------------------------------------------------------------------
extern "C" void kernel_launch(void* const* d_in, const int* in_sizes, int n_in,
                              void* d_out, int out_size, void* d_ws, size_t ws_size,
                              hipStream_t stream) {
    const float* xyz  = (const float*)d_in[0];
    const float* feat = (const float*)d_in[1];
    const float* W1   = (const float*)d_in[2];
    const float* b1   = (const float*)d_in[3];
    const float* W2   = (const float*)d_in[4];
    const float* b2   = (const float*)d_in[5];
    const float* W3   = (const float*)d_in[6];
    const float* b3   = (const float*)d_in[7];

    float* out      = (float*)d_out;
    float* out_xyz  = out;                               // [2,4096,3]
    float* out_feat = out + (size_t)BB * SS * 3;         // [2,128,4096]
    float* out_sidx = out_feat + (size_t)BB * 128 * SS;  // [2,4096]

    char* ws = (char*)d_ws;
    float4* pts4    = (float4*)(ws + WS_PTS4);
    ushort* feat_nc = (ushort*)(ws + WS_FEAT);
    ushort* W1t     = (ushort*)(ws + WS_W1T);
    ushort* W2t     = (ushort*)(ws + WS_W2T);
    ushort* W3t     = (ushort*)(ws + WS_W3T);
    int*    cstart  = (int*)(ws + WS_CSTART);
    int*    cfill   = (int*)(ws + WS_CFILL);
    int*    cid     = (int*)(ws + WS_CID);
    float4* cpts    = (float4*)(ws + WS_CPTS);
    int*    cpidx   = (int*)(ws + WS_CPIDX);

    prep_kernel<<<(T_ALL + 255) / 256, 256, 0, stream>>>(
        xyz, feat, W1, W2, W3, pts4, feat_nc, W1t, W2t, W3t, cid,
        out_xyz, out_sidx);
    histscan_kernel<<<BB, 1024, 0, stream>>>(cid, cstart, cfill);
    scatter_kernel<<<BB * NN / 256, 256, 0, stream>>>(pts4, cid, cfill, cpts, cpidx);
    fused_kernel<<<BB * SS / 2, 128, 0, stream>>>(
        pts4, feat_nc, cstart, cpts, cpidx, W1t, W2t, W3t, b1, b2, b3, out_feat);
}